// Round 3
// baseline (339.293 us; speedup 1.0000x reference)
//
#include <hip/hip_runtime.h>

// GraphConv x3 on MI355X. R11: predicated gather. R10's branch-guarded loads
// serialized (load -> vmcnt(0) -> add per edge, ONE load in flight). Now the
// gather loop has a wave-uniform trip count, issues all 8 uint4 row-loads
// unconditionally, and folds validity into fma (k in {0,1}). nlist is
// zero-filled in prep so out-of-degree slots read row 0 (L1-hot, x0).
// launch_bounds (256,4) so in-flight temps don't spill. 5 dispatches.

#define C128 128
#define CAPN 64     // records per node; mean deg 16, Poisson tail ~1e-18

typedef short s16x8 __attribute__((ext_vector_type(8)));
typedef float f32x4 __attribute__((ext_vector_type(4)));

__device__ __forceinline__ ushort f2bf(float f) {        // RNE fp32->bf16
  unsigned u = __builtin_bit_cast(unsigned, f);
  u = (u + 0x7FFFu + ((u >> 16) & 1u)) >> 16;
  return (ushort)u;
}
__device__ __forceinline__ float bflo(unsigned v) {
  return __builtin_bit_cast(float, v << 16);
}
__device__ __forceinline__ float bfhi(unsigned v) {
  return __builtin_bit_cast(float, v & 0xFFFF0000u);
}
__device__ __forceinline__ unsigned pack2(float lo, float hi) {
  return (unsigned)f2bf(lo) | ((unsigned)f2bf(hi) << 16);
}

// ---------------------------------------------------------------------------
// prep: fused {input dropout fp32->bf16} + {weight pack} + {counter zero} +
// {nlist zero-fill}. Thread partition: [0,n4) dropout, [n4,+96K) pack,
// [+nCnt) zero ncnt, [+Npad*CAPN/8) zero nlist (uint4 strides).
// Wpack idx = (c*8+nt)*512 + lane*8 + j ->
//   W[o=nt*16+(lane&15)][k=(c&3)*32+(lane>>4)*8+j]; c<4 Wrel, c>=4 Wroot.
// ---------------------------------------------------------------------------
__global__ __launch_bounds__(256) void prep_kernel(const float* __restrict__ Wr0,
                                                   const float* __restrict__ Wt0,
                                                   const float* __restrict__ Wr1,
                                                   const float* __restrict__ Wt1,
                                                   const float* __restrict__ Wr2,
                                                   const float* __restrict__ Wt2,
                                                   ushort* __restrict__ Wpack,
                                                   const float* __restrict__ x,
                                                   const void* __restrict__ mask,
                                                   ushort* __restrict__ hdA,
                                                   int n4,
                                                   int* __restrict__ ncnt,
                                                   int nCnt,
                                                   uint4* __restrict__ nlist4,
                                                   int nL4) {
  int t = blockIdx.x * 256 + threadIdx.x;
  if (t < n4) {
    // per-wave mask dtype detect (wave fully inside this branch: n4 % 64 == 0)
    int lane = threadIdx.x & 63;
    unsigned mv = ((const unsigned*)mask)[lane];
    int m32 = (__ballot(mv > 1u) == 0ull);

    float4 v = ((const float4*)x)[t];
    int k0, k1, k2, k3;
    if (m32) {
      int4 m = ((const int4*)mask)[t];
      k0 = m.x; k1 = m.y; k2 = m.z; k3 = m.w;
    } else {
      uchar4 m = ((const uchar4*)mask)[t];
      k0 = m.x; k1 = m.y; k2 = m.z; k3 = m.w;
    }
    ushort4 r;
    r.x = k0 ? f2bf(v.x * 2.5f) : (ushort)0;
    r.y = k1 ? f2bf(v.y * 2.5f) : (ushort)0;
    r.z = k2 ? f2bf(v.z * 2.5f) : (ushort)0;
    r.w = k3 ? f2bf(v.w * 2.5f) : (ushort)0;
    ((ushort4*)hdA)[t] = r;
    return;
  }
  int u = t - n4;
  if (u < 3 * 32768) {
    int L = u >> 15;
    int r = u & 32767;
    int c = r >> 12;
    int nt = (r >> 9) & 7;
    int lane = (r >> 3) & 63;
    int j = r & 7;
    int o = nt * 16 + (lane & 15);
    int k = (c & 3) * 32 + (lane >> 4) * 8 + j;
    const float* src;
    if (L == 0)      src = (c < 4) ? Wr0 : Wt0;
    else if (L == 1) src = (c < 4) ? Wr1 : Wt1;
    else             src = (c < 4) ? Wr2 : Wt2;
    Wpack[u] = f2bf(src[o * C128 + k]);
    return;
  }
  int z = u - 3 * 32768;
  if (z < nCnt) { ncnt[z] = 0; return; }
  int z2 = z - nCnt;
  if (z2 < nL4) {
    uint4 zero; zero.x = 0; zero.y = 0; zero.z = 0; zero.w = 0;
    nlist4[z2] = zero;
  }
}

// ---------------------------------------------------------------------------
// fillb: edge -> per-node list, node-major (ushort src, N<65536).
// Counter line-padded (x16 ints). Edge dtype self-detected per wave.
// ---------------------------------------------------------------------------
__global__ __launch_bounds__(256) void fillb_kernel(const int* __restrict__ eidx,
                                                    int* __restrict__ ncnt,
                                                    ushort* __restrict__ nlist,
                                                    int E) {
  int lane = threadIdx.x & 63;
  unsigned long long be = __ballot(eidx[2 * lane + 1] != 0);
  int e64 = (be == 0ull);   // 1 = edges are int64
  int e = blockIdx.x * 256 + threadIdx.x;
  if (e >= E) return;
  int src, dst;
  if (e64) { src = eidx[2 * e]; dst = eidx[2 * E + 2 * e]; }
  else     { src = eidx[e];     dst = eidx[E + e]; }
  int pos = atomicAdd(&ncnt[dst * 16], 1);
  if (pos < CAPN) nlist[(size_t)dst * CAPN + pos] = (ushort)src;
}

// ---------------------------------------------------------------------------
// Fused layer: block = 16 nodes, 4 waves.
//  0) stage: one coalesced 512B list load per wave (wave w -> nodes 4w..4w+3)
//     + 16 line-padded degree loads; wave-private LDS, no barrier needed.
//  1) gather: wave-uniform trip count; 8 unconditional uint4 row-loads per
//     iteration (all in flight, compiler pipelines with counted vmcnt);
//     validity folded into fma (k in {0,1}); pad slots read row 0 (L1-hot).
//     xor-shfl reduce over quads; quad-0 deposits bf16 rows into As. 1 barrier.
//  2) MFMA: wave w -> col tiles {2w,2w+1}; agg half from LDS, root half
//     loaded post-gather; B frags from Wpack (L2-hot).
//  3) epilogue: mode=1 ReLU + next dropout -> bf16; mode=0 +bias -> fp32.
// ---------------------------------------------------------------------------
__global__ __launch_bounds__(256, 4) void layer_kernel(const ushort* __restrict__ hd,
                                                       const int* __restrict__ ncnt,
                                                       const ushort* __restrict__ nlist,
                                                       const ushort* __restrict__ Wpack,
                                                       const float* __restrict__ bias,
                                                       const void* __restrict__ mask,
                                                       void* __restrict__ outp,
                                                       int mode, int N) {
  __shared__ ushort wl[16][CAPN];   // per-wave 4-row slices (512B/wave)
  __shared__ ushort As[16][136];    // 16 node rows, pad 8 (16B-aligned rows)

  const int tid = threadIdx.x;
  const int wave = tid >> 6, lane = tid & 63;
  const int quad = lane >> 4, l16 = lane & 15, co = l16 * 8;
  const int node0 = blockIdx.x * 16;
  const int nb0 = wave * 4;

  // mask dtype detect (wave-uniform ballot; cheap, L1/L2-hot broadcast)
  int m32 = 0;
  if (mode) {
    unsigned mv = ((const unsigned*)mask)[lane];
    m32 = (__ballot(mv > 1u) == 0ull);
  }

  // ---- 0) stage: degrees + this wave's 4 node lists ----
  int deg16 = ncnt[(node0 + l16) * 16];
  if (deg16 > CAPN) deg16 = CAPN;
  ((uint2*)&wl[nb0][0])[lane] =
      ((const uint2*)(nlist + (size_t)(node0 + nb0) * CAPN))[lane];

  int dc[4];
#pragma unroll
  for (int t = 0; t < 4; ++t) dc[t] = __shfl(deg16, nb0 + t, 64);
  int m = dc[0];
  if (dc[1] > m) m = dc[1];
  if (dc[2] > m) m = dc[2];
  if (dc[3] > m) m = dc[3];

  // ---- 1) gather: predicated, 8 row-loads in flight ----
  const ushort* base = hd + co;
  float ag[4][8];
#pragma unroll
  for (int t = 0; t < 4; ++t)
#pragma unroll
    for (int i = 0; i < 8; ++i) ag[t][i] = 0.f;

  const int iters = (m + 7) >> 3;     // wave-uniform (m is uniform)
  for (int it = 0; it < iters; ++it) {
    const int e = (it << 3) + quad;
    const int e2 = e + 4;
    int id0[4], id1[4];
#pragma unroll
    for (int t = 0; t < 4; ++t) {
      id0[t] = wl[nb0 + t][e];
      id1[t] = wl[nb0 + t][e2];
    }
    uint4 v0[4], v1[4];
#pragma unroll
    for (int t = 0; t < 4; ++t)
      v0[t] = *(const uint4*)(base + (size_t)id0[t] * C128);
#pragma unroll
    for (int t = 0; t < 4; ++t)
      v1[t] = *(const uint4*)(base + (size_t)id1[t] * C128);
#pragma unroll
    for (int t = 0; t < 4; ++t) {
      const float k0 = (e < dc[t]) ? 1.f : 0.f;
      ag[t][0] = fmaf(k0, bflo(v0[t].x), ag[t][0]);
      ag[t][1] = fmaf(k0, bfhi(v0[t].x), ag[t][1]);
      ag[t][2] = fmaf(k0, bflo(v0[t].y), ag[t][2]);
      ag[t][3] = fmaf(k0, bfhi(v0[t].y), ag[t][3]);
      ag[t][4] = fmaf(k0, bflo(v0[t].z), ag[t][4]);
      ag[t][5] = fmaf(k0, bfhi(v0[t].z), ag[t][5]);
      ag[t][6] = fmaf(k0, bflo(v0[t].w), ag[t][6]);
      ag[t][7] = fmaf(k0, bfhi(v0[t].w), ag[t][7]);
      const float k1 = (e2 < dc[t]) ? 1.f : 0.f;
      ag[t][0] = fmaf(k1, bflo(v1[t].x), ag[t][0]);
      ag[t][1] = fmaf(k1, bfhi(v1[t].x), ag[t][1]);
      ag[t][2] = fmaf(k1, bflo(v1[t].y), ag[t][2]);
      ag[t][3] = fmaf(k1, bfhi(v1[t].y), ag[t][3]);
      ag[t][4] = fmaf(k1, bflo(v1[t].z), ag[t][4]);
      ag[t][5] = fmaf(k1, bfhi(v1[t].z), ag[t][5]);
      ag[t][6] = fmaf(k1, bflo(v1[t].w), ag[t][6]);
      ag[t][7] = fmaf(k1, bfhi(v1[t].w), ag[t][7]);
    }
  }
#pragma unroll
  for (int t = 0; t < 4; ++t) {
#pragma unroll
    for (int i = 0; i < 8; ++i) {
      float v = ag[t][i];
      v += __shfl_xor(v, 16, 64);
      v += __shfl_xor(v, 32, 64);
      ag[t][i] = v;
    }
    if (quad == 0) {
      uint4 p;
      p.x = pack2(ag[t][0], ag[t][1]);
      p.y = pack2(ag[t][2], ag[t][3]);
      p.z = pack2(ag[t][4], ag[t][5]);
      p.w = pack2(ag[t][6], ag[t][7]);
      *(uint4*)&As[nb0 + t][co] = p;
    }
  }
  __syncthreads();

  // ---- 2) MFMA. Root frags loaded here (post-gather, TLP hides latency) ----
  int prow = node0 + l16;
  if (prow >= N) prow = N - 1;
  const ushort* hrow = hd + (size_t)prow * C128 + quad * 8;
  s16x8 aroot[4];
#pragma unroll
  for (int c = 0; c < 4; ++c) aroot[c] = *(const s16x8*)(hrow + c * 32);

  f32x4 acc[2];
  acc[0] = (f32x4)0.f;
  acc[1] = (f32x4)0.f;
  const ushort* wp = Wpack + lane * 8;
#pragma unroll
  for (int c = 0; c < 8; ++c) {
    s16x8 afr;
    if (c < 4) afr = *(const s16x8*)&As[l16][c * 32 + quad * 8];
    else       afr = aroot[c - 4];
#pragma unroll
    for (int j = 0; j < 2; ++j) {
      int nt = wave * 2 + j;
      s16x8 bfr = *(const s16x8*)(wp + (c * 8 + nt) * 512);
      acc[j] = __builtin_amdgcn_mfma_f32_16x16x32_bf16(afr, bfr, acc[j], 0, 0, 0);
    }
  }

  // ---- 3) epilogue. C/D layout: col = lane&15, row = quad*4 + reg ----
  if (mode) {
    ushort* ob = (ushort*)outp;
#pragma unroll
    for (int j = 0; j < 2; ++j) {
      int o = (wave * 2 + j) * 16 + l16;
      float bvv = bias[o];
#pragma unroll
      for (int r = 0; r < 4; ++r) {
        int node = node0 + quad * 4 + r;
        if (node >= N) continue;
        size_t idx = (size_t)node * C128 + o;
        int keep = m32 ? ((const int*)mask)[idx]
                       : (int)((const unsigned char*)mask)[idx];
        float v = fmaxf(acc[j][r] + bvv, 0.f);
        ob[idx] = keep ? f2bf(v * 2.5f) : (ushort)0;
      }
    }
  } else {
    float* of = (float*)outp;
#pragma unroll
    for (int j = 0; j < 2; ++j) {
      int o = (wave * 2 + j) * 16 + l16;
      float bvv = bias[o];
#pragma unroll
      for (int r = 0; r < 4; ++r) {
        int node = node0 + quad * 4 + r;
        if (node >= N) continue;
        of[(size_t)node * C128 + o] = acc[j][r] + bvv;
      }
    }
  }
}

// ---------------------------------------------------------------------------
extern "C" void kernel_launch(void* const* d_in, const int* in_sizes, int n_in,
                              void* d_out, int out_size, void* d_ws, size_t ws_size,
                              hipStream_t stream) {
  const float* x      = (const float*)d_in[0];
  const int*   eidx   = (const int*)d_in[1];
  const float* Wrel0  = (const float*)d_in[2];
  const float* Wroot0 = (const float*)d_in[3];
  const float* b0     = (const float*)d_in[4];
  const float* Wrel1  = (const float*)d_in[5];
  const float* Wroot1 = (const float*)d_in[6];
  const float* b1     = (const float*)d_in[7];
  const float* Wrel2  = (const float*)d_in[8];
  const float* Wroot2 = (const float*)d_in[9];
  const float* b2     = (const float*)d_in[10];
  const void*  drop0  = d_in[11];
  const void*  drop1  = d_in[12];
  const void*  drop2  = d_in[13];

  const int N       = in_sizes[0] / C128;
  const int E       = in_sizes[1] / 2;
  const int NC      = N * C128;
  const int nbuck16 = (N + 15) / 16;
  const int Npad    = nbuck16 * 16;
  const int nCnt    = Npad * 16;        // line-padded per-node counters
  const int nL4     = Npad * CAPN / 8;  // nlist size in uint4 units

  char*   ws    = (char*)d_ws;
  ushort* Wpack = (ushort*)ws;                           // 3*32768 bf16
  int*    ncnt  = (int*)(Wpack + 3 * 32768);             // nCnt ints
  ushort* nlist = (ushort*)(ncnt + nCnt);                // Npad*CAPN ushort
  ushort* hdA   = (ushort*)(nlist + (size_t)Npad * CAPN);
  ushort* hdB   = hdA + NC;

  const ushort* Wp0 = Wpack;
  const ushort* Wp1 = Wpack + 32768;
  const ushort* Wp2 = Wpack + 2 * 32768;

  const int n4    = NC / 4;
  const int prepT = n4 + 3 * 32768 + nCnt + nL4;
  prep_kernel<<<(prepT + 255) / 256, 256, 0, stream>>>(
      Wrel0, Wroot0, Wrel1, Wroot1, Wrel2, Wroot2, Wpack,
      x, drop0, hdA, n4, ncnt, nCnt, (uint4*)nlist, nL4);

  fillb_kernel<<<(E + 255) / 256, 256, 0, stream>>>(eidx, ncnt, nlist, E);

  // layer 0: hdA -> hdB (relu + drop1 fused)
  layer_kernel<<<nbuck16, 256, 0, stream>>>(hdA, ncnt, nlist, Wp0, b0, drop1,
                                            hdB, 1, N);
  // layer 1: hdB -> hdA (relu + drop2 fused)
  layer_kernel<<<nbuck16, 256, 0, stream>>>(hdB, ncnt, nlist, Wp1, b1, drop2,
                                            hdA, 1, N);
  // layer 2: hdA -> d_out (fp32)
  layer_kernel<<<nbuck16, 256, 0, stream>>>(hdA, ncnt, nlist, Wp2, b2, nullptr,
                                            d_out, 0, N);
}